// Round 3
// 800.536 us; speedup vs baseline: 1.0410x; 1.0410x over previous
//
#include <hip/hip_runtime.h>
#include <hip/hip_bf16.h>

#define NN 20000
#define EE 640000
#define DD 64

// ---------------- CSR build ----------------

__global__ void zero_kernel(int* __restrict__ p, int n) {
    int i = blockIdx.x * blockDim.x + threadIdx.x;
    if (i < n) p[i] = 0;
}

__global__ void hist_kernel(const int* __restrict__ col, int* __restrict__ counts) {
    int e = blockIdx.x * blockDim.x + threadIdx.x;
    if (e < EE) {
        int c = col[e];
        if ((unsigned)c >= NN) c = 0;   // insurance: never OOB
        atomicAdd(&counts[c], 1);
    }
}

__global__ void scan_kernel(const int* __restrict__ counts, int* __restrict__ offsets) {
    const int T = 1024;
    const int per = (NN + T - 1) / T;   // 20
    int tid = threadIdx.x;
    int start = tid * per;
    int s = 0;
    for (int i = 0; i < per; ++i) { int idx = start + i; if (idx < NN) s += counts[idx]; }
    __shared__ int sm[T];
    sm[tid] = s;
    __syncthreads();
    for (int off = 1; off < T; off <<= 1) {
        int t = (tid >= off) ? sm[tid - off] : 0;
        __syncthreads();
        sm[tid] += t;
        __syncthreads();
    }
    int run = sm[tid] - s;  // exclusive prefix of this thread's chunk
    for (int i = 0; i < per; ++i) {
        int idx = start + i;
        if (idx < NN) { offsets[idx] = run; run += counts[idx]; }
    }
    if (tid == T - 1) offsets[NN] = sm[T - 1];
}

__global__ void scatter_kernel(const int* __restrict__ row, const int* __restrict__ col,
                               const int* __restrict__ offsets, int* __restrict__ cursor,
                               int* __restrict__ srcs) {
    int e = blockIdx.x * blockDim.x + threadIdx.x;
    if (e < EE) {
        int c = col[e];
        if ((unsigned)c >= NN) c = 0;   // must match hist's clamp
        int r = row[e];
        if ((unsigned)r >= NN) r = 0;
        int p = atomicAdd(&cursor[c], 1);
        srcs[offsets[c] + p] = r;
    }
}

// ---------------- Phase 1: hs[n][0:64] = x[n]@w[n]; hs[n][64:128] = att[n][64:128]; s1[n] ----

__global__ __launch_bounds__(256) void node_h_kernel(
    const float* __restrict__ x,                   // f32 [N,64]
    const float* __restrict__ w,                   // f32 [N,64,64]
    const float* __restrict__ att,                 // f32 [N,128]
    float* __restrict__ hs,                        // f32 [N,128]  (h | a2)
    float* __restrict__ s1)                        // f32 [N]
{
    int wave = (blockIdx.x * blockDim.x + threadIdx.x) >> 6;
    int lane = threadIdx.x & 63;
    if (wave >= NN) return;
    int n = wave;

    float xval = x[(size_t)n * 64 + lane];

    int eg = lane & 15;
    int dg = lane >> 4;
    float acc[4] = {0.f, 0.f, 0.f, 0.f};

    const float* wbase = w + (size_t)n * 4096;
    #pragma unroll
    for (int it = 0; it < 16; ++it) {
        int d = it * 4 + dg;
        float xv = __shfl(xval, d, 64);
        float4 r = *(const float4*)(wbase + d * 64 + eg * 4);
        acc[0] += xv * r.x;
        acc[1] += xv * r.y;
        acc[2] += xv * r.z;
        acc[3] += xv * r.w;
    }
    #pragma unroll
    for (int j = 0; j < 4; ++j) {
        acc[j] += __shfl_xor(acc[j], 16, 64);
        acc[j] += __shfl_xor(acc[j], 32, 64);
    }
    // lanes 0..15 hold full h[n][eg*4..eg*4+3]
    if (dg == 0) {
        *(float4*)(hs + (size_t)n * 128 + eg * 4) = make_float4(acc[0], acc[1], acc[2], acc[3]);
    }
    // copy a2 half next to h for one-row gather locality in phase 2
    hs[(size_t)n * 128 + 64 + lane] = att[(size_t)n * 128 + 64 + lane];

    // s1 = h[n] . att[n][0:64]
    float4 a = *(const float4*)(att + (size_t)n * 128 + eg * 4);
    float p = acc[0] * a.x + acc[1] * a.y + acc[2] * a.z + acc[3] * a.w;
    p += __shfl_xor(p, 1, 64);
    p += __shfl_xor(p, 2, 64);
    p += __shfl_xor(p, 4, 64);
    p += __shfl_xor(p, 8, 64);
    if (lane == 0) s1[n] = p;
}

// ---------------- Phase 2: fused softmax + aggregate, one wave per destination node ----------------
// Restructured: 16-lane group per edge. lane = g*16 + q; group g handles edge slot g,
// lane q holds dims 4q..4q+3 as float4. Dot product = 4 in-lane FMAs + 4-step xor
// reduce within the 16-lane group (xor 1,2 = DPP quad-perm, xor 8 = row rotate; only
// xor 4 hits the DS pipe) instead of the previous 6-deep 64-lane chain PER EDGE.
// Unroll x2 -> 8 edges in flight per iteration for memory-level parallelism.
// No max-subtraction: scores are O(+-5) by construction; softmax is shift-invariant,
// exact in math and safe in f32 (overflow needs >88).

template<bool LAYER0>
__global__ __launch_bounds__(256) void edge_aggr_kernel(
    const float* __restrict__ hs,                  // f32 [N,128] (h | a2)
    const float* __restrict__ s1,                  // f32 [N]
    const float* __restrict__ bias,                // f32 [64]
    const int* __restrict__ offsets,               // [N+1]
    const int* __restrict__ srcs,                  // [E] source ids grouped by dest
    float* __restrict__ out)                       // layer0: xmid (relu'd); layer1: d_out
{
    int wave = (blockIdx.x * blockDim.x + threadIdx.x) >> 6;
    int lane = threadIdx.x & 63;
    if (wave >= NN) return;
    int c = wave;
    int g = lane >> 4;        // edge slot within iteration (0..3)
    int q = lane & 15;        // dim quarter: holds dims 4q..4q+3

    // all 4 groups load the same 64 floats of h[c] -> broadcast from L1
    float4 hcv = *(const float4*)(hs + (size_t)c * 128 + q * 4);
    int beg = offsets[c];
    int end = offsets[c + 1];

    float4 acc0 = make_float4(0.f, 0.f, 0.f, 0.f);
    float4 acc1 = make_float4(0.f, 0.f, 0.f, 0.f);
    float sum0 = 0.f, sum1 = 0.f;

    for (int ib = beg; ib < end; ib += 8) {
        int i0 = ib + g;
        int i1 = ib + 4 + g;
        bool v0 = i0 < end;
        bool v1 = i1 < end;
        // exec-masked loads: invalid slots never touch srcs[] (no OOB), use row 0
        int r0 = 0, r1 = 0;
        if (v0) { r0 = srcs[i0]; if ((unsigned)r0 >= NN) r0 = 0; }
        if (v1) { r1 = srcs[i1]; if ((unsigned)r1 >= NN) r1 = 0; }
        const float* p0 = hs + (size_t)r0 * 128;
        const float* p1 = hs + (size_t)r1 * 128;
        float4 a0 = *(const float4*)(p0 + 64 + q * 4);
        float4 a1 = *(const float4*)(p1 + 64 + q * 4);
        float4 h0 = *(const float4*)(p0 + q * 4);
        float4 h1 = *(const float4*)(p1 + q * 4);
        float t0 = s1[r0];
        float t1 = s1[r1];

        float d0 = hcv.x * a0.x;
        d0 = fmaf(hcv.y, a0.y, d0);
        d0 = fmaf(hcv.z, a0.z, d0);
        d0 = fmaf(hcv.w, a0.w, d0);
        float d1 = hcv.x * a1.x;
        d1 = fmaf(hcv.y, a1.y, d1);
        d1 = fmaf(hcv.z, a1.z, d1);
        d1 = fmaf(hcv.w, a1.w, d1);
        // reduce across the 16 lanes of the group (two chains interleaved)
        d0 += __shfl_xor(d0, 1, 64);  d1 += __shfl_xor(d1, 1, 64);
        d0 += __shfl_xor(d0, 2, 64);  d1 += __shfl_xor(d1, 2, 64);
        d0 += __shfl_xor(d0, 4, 64);  d1 += __shfl_xor(d1, 4, 64);
        d0 += __shfl_xor(d0, 8, 64);  d1 += __shfl_xor(d1, 8, 64);

        float sc0 = d0 + t0; sc0 = (sc0 >= 0.f) ? sc0 : 0.2f * sc0;
        float sc1 = d1 + t1; sc1 = (sc1 >= 0.f) ? sc1 : 0.2f * sc1;
        float e0 = v0 ? __expf(sc0) : 0.f;
        float e1 = v1 ? __expf(sc1) : 0.f;
        sum0 += e0;
        sum1 += e1;
        acc0.x = fmaf(e0, h0.x, acc0.x);
        acc0.y = fmaf(e0, h0.y, acc0.y);
        acc0.z = fmaf(e0, h0.z, acc0.z);
        acc0.w = fmaf(e0, h0.w, acc0.w);
        acc1.x = fmaf(e1, h1.x, acc1.x);
        acc1.y = fmaf(e1, h1.y, acc1.y);
        acc1.z = fmaf(e1, h1.z, acc1.z);
        acc1.w = fmaf(e1, h1.w, acc1.w);
    }

    float sum = sum0 + sum1;
    float4 acc;
    acc.x = acc0.x + acc1.x;
    acc.y = acc0.y + acc1.y;
    acc.z = acc0.z + acc1.z;
    acc.w = acc0.w + acc1.w;

    // one cross-group reduce per NODE (was per edge before)
    sum   += __shfl_xor(sum,   16, 64);  sum   += __shfl_xor(sum,   32, 64);
    acc.x += __shfl_xor(acc.x, 16, 64);  acc.x += __shfl_xor(acc.x, 32, 64);
    acc.y += __shfl_xor(acc.y, 16, 64);  acc.y += __shfl_xor(acc.y, 32, 64);
    acc.z += __shfl_xor(acc.z, 16, 64);  acc.z += __shfl_xor(acc.z, 32, 64);
    acc.w += __shfl_xor(acc.w, 16, 64);  acc.w += __shfl_xor(acc.w, 32, 64);

    if (g == 0) {
        float4 b4 = *(const float4*)(bias + q * 4);
        float4 o;
        if (end > beg) {
            o.x = acc.x / sum + b4.x;
            o.y = acc.y / sum + b4.y;
            o.z = acc.z / sum + b4.z;
            o.w = acc.w / sum + b4.w;
        } else {
            o = b4;
        }
        if (LAYER0) {
            o.x = fmaxf(o.x, 0.f);
            o.y = fmaxf(o.y, 0.f);
            o.z = fmaxf(o.z, 0.f);
            o.w = fmaxf(o.w, 0.f);
        }
        *(float4*)(out + (size_t)c * 64 + q * 4) = o;
    }
}

// ---------------- launch ----------------

extern "C" void kernel_launch(void* const* d_in, const int* in_sizes, int n_in,
                              void* d_out, int out_size, void* d_ws, size_t ws_size,
                              hipStream_t stream) {
    const float* x    = (const float*)d_in[0];   // f32 [N,64]
    const int*   ei   = (const int*)d_in[1];     // int32 [2,E]
    const float* w0   = (const float*)d_in[2];   // f32 [N,64,64]
    const float* att0 = (const float*)d_in[3];   // f32 [N,128]
    const float* b0   = (const float*)d_in[4];   // f32 [64]
    const float* w1   = (const float*)d_in[5];
    const float* att1 = (const float*)d_in[6];
    const float* b1   = (const float*)d_in[7];

    const int* row = ei;        // source
    const int* col = ei + EE;   // destination

    char* base = (char*)d_ws;
    float* hs      = (float*)(base);                    // 10,240,000 B  [N,128]
    float* xmid    = (float*)(base + 10240000);         //  5,120,000 B
    float* s1      = (float*)(base + 15360000);         //     80,000 B
    int*   counts  = (int*)(base + 15440000);           //     80,000 B
    int*   cursor  = (int*)(base + 15520000);           //     80,000 B (contiguous with counts)
    int*   offsets = (int*)(base + 15600000);           //     80,004 B (padded)
    int*   srcs    = (int*)(base + 15680016);           //  2,560,000 B  (total ~18.2 MB)

    // CSR build (ws re-poisoned every call, so rebuild each launch)
    zero_kernel<<<(2 * NN + 255) / 256, 256, 0, stream>>>(counts, 2 * NN);  // counts + cursor
    hist_kernel<<<(EE + 255) / 256, 256, 0, stream>>>(col, counts);
    scan_kernel<<<1, 1024, 0, stream>>>(counts, offsets);
    scatter_kernel<<<(EE + 255) / 256, 256, 0, stream>>>(row, col, offsets, cursor, srcs);

    const int hblocks = (NN + 3) / 4;   // 4 waves/block, 1 wave/node

    // layer 0
    node_h_kernel<<<hblocks, 256, 0, stream>>>(x, w0, att0, hs, s1);
    edge_aggr_kernel<true><<<hblocks, 256, 0, stream>>>(hs, s1, b0, offsets, srcs, xmid);
    // layer 1
    node_h_kernel<<<hblocks, 256, 0, stream>>>(xmid, w1, att1, hs, s1);
    edge_aggr_kernel<false><<<hblocks, 256, 0, stream>>>(hs, s1, b1, offsets, srcs,
                                                         (float*)d_out);
}